// Round 6
// baseline (173.520 us; speedup 1.0000x reference)
//
#include <hip/hip_runtime.h>

// Problem constants (fixed by the reference):
//   TOTAL_NODES = 262144, NUM_GRAPHS = 1024, MAX_NODES = 512, D = 256
#define NUM_GRAPHS 1024
#define MAX_NODES  512
#define DIM        256
#define D4         (DIM / 4)          // 64 float4 per row (1 KB)

typedef float f4 __attribute__((ext_vector_type(4)));

// lower_bound over the sorted batch_idx (int64 or int32 storage).
__device__ __forceinline__ int lower_bound_idx(const int* __restrict__ b, int n,
                                               bool is64, int key) {
    int lo = 0, hi = n;
    while (lo < hi) {
        int mid = (lo + hi) >> 1;
        int v = is64 ? b[2 * mid] : b[mid];
        if (v < key) lo = mid + 1; else hi = mid;
    }
    return lo;
}

// ---------------------------------------------------------------------------
// Single fused kernel, ONE BLOCK PER GRAPH. Every block has identical work
// (read ~counts[g] rows ≈ 256 KB, write 512 rows = 512 KB + 2 KB mask), so
// CU-level load balance is perfect under any dispatch policy. (The previous
// 2-blocks-per-graph version was bimodal copy-vs-fill per block, and with
// 2048 blocks round-robined over 256 CUs each CU got only one parity —
// half the CUs did all the reads while the others idled: 4.7 TB/s.)
// Threads 0/1 binary-search starts[g] / starts[g+1] directly (bidx is
// L2/L3-resident; ~18 dependent loads, in parallel across 1024 blocks).
// Each wave streams a contiguous 128-row (128 KB) range: copy loop for
// occupied rows, then zero-fill loop. Plain cached loads/stores — the
// config the 6.3 TB/s copy / 6.7 TB/s fill ceilings use.
// ---------------------------------------------------------------------------
__global__ void __launch_bounds__(256)
scatter_states_kernel(const f4* __restrict__ emb,
                      const int* __restrict__ bidx32, int n,
                      f4* __restrict__ out, float* __restrict__ mask) {
    __shared__ int sc[2];
    const int g = blockIdx.x;               // 0..1023

    if (threadIdx.x < 2) {
        // int64 detect: little-endian int64 values < 2^31 => int32 view at
        // index n-1 is a hi-word == 0; int32 => it's the max graph id (!=0).
        const bool is64 = (bidx32[n - 1] == 0);
        sc[threadIdx.x] = lower_bound_idx(bidx32, n, is64, g + threadIdx.x);
    }
    __syncthreads();
    const int s = sc[0];
    const int c = sc[1] - sc[0];

    const int lane  = threadIdx.x & 63;
    const int w     = threadIdx.x >> 6;     // wave 0..3
    const int rbase = w * 128;              // this wave's first row

    // Per-wave contiguous streams: 128 rows x 1 KB.
    const f4* wemb = emb + (size_t)(s + rbase) * D4 + lane;
    f4*       wout = out + ((size_t)g * MAX_NODES + rbase) * D4 + lane;

    int ncopy = c - rbase;                  // occupied rows in this range
    ncopy = ncopy < 0 ? 0 : (ncopy > 128 ? 128 : ncopy);

    int it = 0;
#pragma unroll 8
    for (; it < ncopy; ++it)
        wout[it * D4] = wemb[it * D4];
    const f4 z = (f4)(0.f);
#pragma unroll 8
    for (; it < 128; ++it)
        wout[it * D4] = z;

    // enc_mask: 512 elements for this graph, 2 per thread (f32 0/1).
    float* mg = mask + (size_t)g * MAX_NODES;
    mg[threadIdx.x]       = (threadIdx.x < c)       ? 1.0f : 0.0f;
    mg[256 + threadIdx.x] = (256 + (int)threadIdx.x < c) ? 1.0f : 0.0f;
}

extern "C" void kernel_launch(void* const* d_in, const int* in_sizes, int n_in,
                              void* d_out, int out_size, void* d_ws, size_t ws_size,
                              hipStream_t stream) {
    const float* node_emb = (const float*)d_in[0];
    const int*   bidx32   = (const int*)d_in[1];   // int32 view; kernel detects int64
    const int    n        = in_sizes[1];           // 262144

    float* mask = (float*)d_out + (size_t)NUM_GRAPHS * MAX_NODES * DIM;
    scatter_states_kernel<<<NUM_GRAPHS, 256, 0, stream>>>(
        (const f4*)node_emb, bidx32, n, (f4*)d_out, mask);
}